// Round 2
// baseline (17336.159 us; speedup 1.0000x reference)
//
#include <hip/hip_runtime.h>
#include <math.h>

#define BB 8
#define TT 4096
#define DD 512
constexpr float LRF = 0.01f;

// ---------------- workspace layout (floats) ----------------
// A  : [4096][512]   CU : [4096][512]   G : [16][256][256]
// P  : [256][512]    BV : [64][512]     W : [512][512]
// WS : [16][512][512] S : [16][2048][256]  BAR: 64 (one uint used)
#define OFF_A  0
#define OFF_CU 2097152
#define OFF_G  4194304
#define OFF_P  5242880
#define OFF_BV 5373952
#define OFF_W  5406720
#define OFF_WS 5668864
#define OFF_S  9863168
#define OFF_BAR 18251776
// total = 18251840 floats = 69.63 MiB

// ---------- software grid barrier (regular launch, 256 resident blocks) ----------
// ticket-generation protocol: every barrier call adds exactly 256 to the counter.
__device__ __forceinline__ void gbar(unsigned int* bar) {
    __syncthreads();                       // all waves of block done (incl. vmcnt drain)
    if (threadIdx.x == 0) {
        __threadfence();                   // release: writeback L2 (agent scope)
        unsigned int ticket = atomicAdd(bar, 1u);
        unsigned int target = (ticket & ~255u) + 256u;   // (gen+1)*256
        while (__hip_atomic_load(bar, __ATOMIC_RELAXED, __HIP_MEMORY_SCOPE_AGENT) < target)
            __builtin_amdgcn_s_sleep(2);
        __threadfence();                   // acquire: invalidate L1 + XCD L2
    }
    __syncthreads();
}

// ---------- shared 64x64 tile helpers (pad-65 LDS, 4x4 micro) ----------
__device__ __forceinline__ void mm_stage(const float* ga, const float* gbm,
                                         float* L0, float* L1, int tid) {
    for (int l = tid; l < 64 * 16; l += 256) {
        int r = l >> 4, c4 = (l & 15) * 4;
        float4 v = *(const float4*)&ga[r * DD + c4];
        L0[r * 65 + c4] = v.x; L0[r * 65 + c4 + 1] = v.y;
        L0[r * 65 + c4 + 2] = v.z; L0[r * 65 + c4 + 3] = v.w;
        float4 u = *(const float4*)&gbm[r * DD + c4];
        L1[r * 65 + c4] = u.x; L1[r * 65 + c4 + 1] = u.y;
        L1[r * 65 + c4 + 2] = u.z; L1[r * 65 + c4 + 3] = u.w;
    }
}

// C[64][64] += A_tile[64][512] * B_tile[64][512]^T ; ga/gbm point at tile row 0
__device__ __forceinline__ void mm_tile(const float* ga, const float* gbm,
                                        float* L0, float* L1, int tid, int r0, int c0,
                                        float acc[4][4]) {
    for (int kt = 0; kt < 8; ++kt) {
        __syncthreads();   // leading sync: safe for repeated tiles in one block
        mm_stage(ga + kt * 64, gbm + kt * 64, L0, L1, tid);
        __syncthreads();
        for (int kk = 0; kk < 64; ++kk) {
            float af[4], bf[4];
#pragma unroll
            for (int q = 0; q < 4; ++q) { af[q] = L0[(r0 + q) * 65 + kk]; bf[q] = L1[(c0 + q) * 65 + kk]; }
#pragma unroll
            for (int q = 0; q < 4; ++q)
#pragma unroll
                for (int w2 = 0; w2 < 4; ++w2) acc[q][w2] += af[q] * bf[w2];
        }
    }
}

// out[row][i] += LR * sum_{s<tloc} S[p][rloc][s] * cu[p*256+s][i]   (one 64x64 tile)
__device__ __forceinline__ void apply_tile(const float* S, const float* CU, float* out,
                                           int t_, float* L0, float* L1, int tid, int r0, int c0) {
    int it = t_ & 7, rt = (t_ >> 3) & 31, p = t_ >> 8;
    float acc[4][4] = {};
    for (int kt = 0; kt < 4; ++kt) {
        __syncthreads();
        for (int l = tid; l < 64 * 16; l += 256) {
            int r = l >> 4, c4 = (l & 15) * 4;
            int rloc = rt * 64 + r;
            int tq = rloc & 255;
            float4 v = *(const float4*)&S[(p * 2048 + rloc) * 256 + kt * 64 + c4];
            int sb = kt * 64 + c4;
            L0[r * 65 + c4]     = (sb + 0 < tq) ? v.x : 0.f;
            L0[r * 65 + c4 + 1] = (sb + 1 < tq) ? v.y : 0.f;
            L0[r * 65 + c4 + 2] = (sb + 2 < tq) ? v.z : 0.f;
            L0[r * 65 + c4 + 3] = (sb + 3 < tq) ? v.w : 0.f;
            float4 u = *(const float4*)&CU[(p * 256 + kt * 64 + r) * DD + it * 64 + c4];
            L1[r * 65 + c4] = u.x; L1[r * 65 + c4 + 1] = u.y;
            L1[r * 65 + c4 + 2] = u.z; L1[r * 65 + c4 + 3] = u.w;
        }
        __syncthreads();
        for (int kk = 0; kk < 64; ++kk) {
            float af[4], bf[4];
#pragma unroll
            for (int q = 0; q < 4; ++q) { af[q] = L0[(r0 + q) * 65 + kk]; bf[q] = L1[kk * 65 + c0 + q]; }
#pragma unroll
            for (int q = 0; q < 4; ++q)
#pragma unroll
                for (int w2 = 0; w2 < 4; ++w2) acc[q][w2] += af[q] * bf[w2];
        }
    }
#pragma unroll
    for (int q = 0; q < 4; ++q) {
        int rloc = rt * 64 + r0 + q;
        int grow = ((rloc >> 8) * TT) + p * 256 + (rloc & 255);
        float4 cur = *(float4*)&out[grow * DD + it * 64 + c0];
        cur.x += LRF * acc[q][0]; cur.y += LRF * acc[q][1];
        cur.z += LRF * acc[q][2]; cur.w += LRF * acc[q][3];
        *(float4*)&out[grow * DD + it * 64 + c0] = cur;
    }
}

// intra-chunk sequential scan (one block, 256 threads; thread = dims d, d+256)
__device__ void scan_role(const float* BV, const float* G, float* CU, int kchunk,
                          float* lds, int tid) {
    float* gl = lds;            // 64*64
    float* part = lds + 4096;   // [2][4]
    int wid = tid >> 6, lane = tid & 63;
    int p = kchunk >> 2, j = kchunk & 3;
    const float* Gp = G + p * 65536;
    for (int l = tid; l < 64 * 16; l += 256) {
        int r = l >> 4, c4 = (l & 15) * 4;
        float4 v = *(const float4*)&Gp[(j * 64 + r) * 256 + j * 64 + c4];
        *(float4*)&gl[r * 64 + c4] = v;
    }
    float acc0[64], acc1[64];
#pragma unroll
    for (int t = 0; t < 64; ++t) {
        acc0[t] = BV[t * DD + tid];
        acc1[t] = BV[t * DD + tid + 256];
    }
    __syncthreads();
    float* cup = CU + (p * 256 + j * 64) * DD;
#pragma unroll
    for (int s = 0; s < 64; ++s) {
        float u0 = acc0[s], u1 = acc1[s];
        float v = u0 * u0 + u1 * u1;
#pragma unroll
        for (int off = 32; off > 0; off >>= 1) v += __shfl_xor(v, off, 64);
        if (lane == 0) part[(s & 1) * 4 + wid] = v;
        __syncthreads();
        float n2u = part[(s & 1) * 4 + 0] + part[(s & 1) * 4 + 1]
                  + part[(s & 1) * 4 + 2] + part[(s & 1) * 4 + 3];
        float n2 = n2u * gl[s * 64 + s];                      // ||u||^2 * ||a||^2
        float cs = (n2 > 0.25f) ? 0.5f * rsqrtf(n2) : 1.0f;  // min(1, CLIP/n)
        cup[s * DD + tid] = cs * u0;
        cup[s * DD + tid + 256] = cs * u1;
        float w0 = (LRF * cs) * u0, w1 = (LRF * cs) * u1;
        int t0 = s + 1;
#pragma unroll
        for (; t0 < 64 && (t0 & 3); ++t0) {
            float g = gl[s * 64 + t0];
            acc0[t0] -= g * w0; acc1[t0] -= g * w1;
        }
#pragma unroll
        for (; t0 < 64; t0 += 4) {
            float4 g4 = *(const float4*)&gl[s * 64 + t0];
            acc0[t0]     -= g4.x * w0; acc1[t0]     -= g4.x * w1;
            acc0[t0 + 1] -= g4.y * w0; acc1[t0 + 1] -= g4.y * w1;
            acc0[t0 + 2] -= g4.z * w0; acc1[t0 + 2] -= g4.z * w1;
            acc0[t0 + 3] -= g4.w * w0; acc1[t0 + 3] -= g4.w * w1;
        }
    }
}

// =====================================================================
// ONE kernel (regular launch, 256 blocks x 256 threads, all resident)
// with software grid barriers. Phase roles by blockIdx:
//   corr phase : blk 0-7 corr(p,j);  blk 8-71 apply tiles of superchunk p-1
//   scan phase : blk 0 scan;  blk 1-32 score tiles;  blk 33-96 mem tiles
// Exact-fit schedules: score 2048=64x32, mem 4096=64x64 (phase k=4p+j carries
// exactly superchunk p -> WS[p] ready), apply 15x256 during p for p-1 + 256 tail.
// =====================================================================
__global__ __launch_bounds__(256) void tm_seq(
    const float* __restrict__ x, const float* __restrict__ Wc0, const float* __restrict__ Wb,
    float* A, float* CU, float* G, float* P, float* BV, float* W, float* WS, float* S,
    float* out, float* outW, unsigned int* bar)
{
    const int bid = blockIdx.x;
    const int tid = threadIdx.x;
    const int c0 = (tid & 15) * 4, r0 = (tid >> 4) * 4;

    __shared__ float lds[2 * 64 * 65 + 16];
    float* L0 = lds;
    float* L1 = lds + 64 * 65;

    // ---- phase 0: batch-mean of x + W init/snapshot(0) ----
    for (int it = 0; it < 32; ++it) {
        int idx = (bid * 32 + it) * 256 + tid;
        float s = 0.f;
#pragma unroll
        for (int b = 0; b < BB; ++b) s += x[b * (TT * DD) + idx];
        A[idx] = s * 0.125f;
    }
    for (int it = 0; it < 4; ++it) {
        int idx = (bid * 4 + it) * 256 + tid;
        float v = Wb[idx] + Wc0[idx];
        W[idx] = v; WS[idx] = v;
    }
    gbar(bar);

    // ---- phase 1: Gram tiles (all 256 blocks) + P(0) (blocks 0..31) ----
    {
        int p = bid >> 4, ts = (bid >> 2) & 3, ttl = bid & 3;
        float acc[4][4] = {};
        mm_tile(A + (p * 256 + ts * 64) * DD, A + (p * 256 + ttl * 64) * DD,
                L0, L1, tid, r0, c0, acc);
#pragma unroll
        for (int q = 0; q < 4; ++q)
            *(float4*)&G[p * 65536 + (ts * 64 + r0 + q) * 256 + ttl * 64 + c0] =
                make_float4(acc[q][0], acc[q][1], acc[q][2], acc[q][3]);
    }
    if (bid < 32) {
        int bt = bid & 3, bi = bid >> 2;
        float acc[4][4] = {};
        mm_tile(A + bt * 64 * DD, W + bi * 64 * DD, L0, L1, tid, r0, c0, acc);
#pragma unroll
        for (int q = 0; q < 4; ++q) {
            float4 av = *(const float4*)&A[(bt * 64 + r0 + q) * DD + bi * 64 + c0];
            *(float4*)&P[(bt * 64 + r0 + q) * DD + bi * 64 + c0] =
                make_float4(av.x - acc[q][0], av.y - acc[q][1], av.z - acc[q][2], av.w - acc[q][3]);
        }
    }
    gbar(bar);

    // ---- main sequential loop over 16 superchunks ----
    for (int p = 0; p < 16; ++p) {
        for (int j = 0; j < 4; ++j) {
            // ======== corr phase ========
            if (bid < 8) {
                const float* Gp = G + p * 65536;
                int bd = bid;
                float acc[4][4] = {};
                for (int kb = 0; kb < j * 64; kb += 64) {
                    __syncthreads();
                    for (int l = tid; l < 64 * 16; l += 256) {
                        int r = l >> 4, c4 = (l & 15) * 4;
                        float4 v = *(const float4*)&Gp[(kb + r) * 256 + j * 64 + c4];
                        L0[r * 65 + c4] = v.x; L0[r * 65 + c4 + 1] = v.y;
                        L0[r * 65 + c4 + 2] = v.z; L0[r * 65 + c4 + 3] = v.w;
                        float4 u = *(const float4*)&CU[(p * 256 + kb + r) * DD + bd * 64 + c4];
                        L1[r * 65 + c4] = u.x; L1[r * 65 + c4 + 1] = u.y;
                        L1[r * 65 + c4 + 2] = u.z; L1[r * 65 + c4 + 3] = u.w;
                    }
                    __syncthreads();
                    for (int kk = 0; kk < 64; ++kk) {
                        float gf[4], cf[4];
#pragma unroll
                        for (int q = 0; q < 4; ++q) { gf[q] = L0[kk * 65 + r0 + q]; cf[q] = L1[kk * 65 + c0 + q]; }
#pragma unroll
                        for (int q = 0; q < 4; ++q)
#pragma unroll
                            for (int w2 = 0; w2 < 4; ++w2) acc[q][w2] += gf[q] * cf[w2];
                    }
                }
#pragma unroll
                for (int q = 0; q < 4; ++q) {
                    float4 pv = *(const float4*)&P[(j * 64 + r0 + q) * DD + bd * 64 + c0];
                    *(float4*)&BV[(r0 + q) * DD + bd * 64 + c0] =
                        make_float4(pv.x - LRF * acc[q][0], pv.y - LRF * acc[q][1],
                                    pv.z - LRF * acc[q][2], pv.w - LRF * acc[q][3]);
                }
            } else if (bid < 72 && p > 0) {
                // apply tiles for superchunk p-1 (CU[p-1], S[p-1], out rows all ready)
                int t_ = (p - 1) * 256 + j * 64 + (bid - 8);
                apply_tile(S, CU, out, t_, L0, L1, tid, r0, c0);
            }
            gbar(bar);

            // ======== scan phase ========
            int k = p * 4 + j;
            if (bid == 0) {
                scan_role(BV, G, CU, k, lds, tid);
            } else if (bid < 33) {
                // score tile: needs only A (phase 0)
                int t_ = k * 32 + (bid - 1);
                int st = t_ & 3, rt = (t_ >> 2) & 31, ps = t_ >> 7;
                int growbase = (rt >> 2) * TT + ps * 256 + (rt & 3) * 64;
                float acc[4][4] = {};
                mm_tile(x + growbase * DD, A + (ps * 256 + st * 64) * DD,
                        L0, L1, tid, r0, c0, acc);
#pragma unroll
                for (int q = 0; q < 4; ++q)
                    *(float4*)&S[(ps * 2048 + rt * 64 + r0 + q) * 256 + st * 64 + c0] =
                        make_float4(acc[q][0], acc[q][1], acc[q][2], acc[q][3]);
            } else if (bid < 97) {
                // mem tile: phase k=4p+j carries exactly superchunk p -> WS[p] ready
                int t_ = k * 64 + (bid - 33);
                int pm = t_ >> 8, rem = t_ & 255, rt = rem >> 3, itile = rem & 7;
                int growbase = (rt >> 2) * TT + pm * 256 + (rt & 3) * 64;
                float acc[4][4] = {};
                mm_tile(x + growbase * DD, WS + pm * DD * DD + itile * 64 * DD,
                        L0, L1, tid, r0, c0, acc);
#pragma unroll
                for (int q = 0; q < 4; ++q)
                    *(float4*)&out[(growbase + r0 + q) * DD + itile * 64 + c0] =
                        make_float4(acc[q][0], acc[q][1], acc[q][2], acc[q][3]);
            }
            gbar(bar);
        }

        // ======== W update (+snapshot p+1 / final outW) : all 256 blocks ========
        for (int it = 0; it < 4; ++it) {
            int idx = (bid * 4 + it) * 256 + tid;
            int i = idx >> 9, jj = idx & 511;
            const float* cb = CU + p * 256 * DD + i;
            const float* ab = A + p * 256 * DD + jj;
            float s = 0.f;
#pragma unroll 8
            for (int r = 0; r < 256; ++r) s += cb[r * DD] * ab[r * DD];
            float w = W[idx] + LRF * s;
            W[idx] = w;
            if (p < 15) WS[(p + 1) * DD * DD + idx] = w;
            else outW[idx] = w - Wb[idx];
        }
        gbar(bar);

        // ======== next P : blocks 0..31 ========
        if (p < 15) {
            if (bid < 32) {
                int bt = bid & 3, bi = bid >> 2;
                float acc[4][4] = {};
                mm_tile(A + ((p + 1) * 256 + bt * 64) * DD, W + bi * 64 * DD,
                        L0, L1, tid, r0, c0, acc);
#pragma unroll
                for (int q = 0; q < 4; ++q) {
                    float4 av = *(const float4*)&A[((p + 1) * 256 + bt * 64 + r0 + q) * DD + bi * 64 + c0];
                    *(float4*)&P[(bt * 64 + r0 + q) * DD + bi * 64 + c0] =
                        make_float4(av.x - acc[q][0], av.y - acc[q][1], av.z - acc[q][2], av.w - acc[q][3]);
                }
            }
            gbar(bar);
        }
    }

    // ---- tail: apply tiles for superchunk 15 (one per block) ----
    {
        int t_ = 15 * 256 + bid;
        apply_tile(S, CU, out, t_, L0, L1, tid, r0, c0);
    }
}

// out[row][i] *= sigmoid(x[row] . gate_w[i] + gate_b[i])   (unchanged)
__global__ __launch_bounds__(256) void tm_gate(const float* __restrict__ x, const float* __restrict__ gw,
                                               const float* __restrict__ gb, float* __restrict__ out) {
    __shared__ float al[64 * 65];
    __shared__ float bl[64 * 65];
    int bid = blockIdx.x;
    int it = bid & 7, rt = bid >> 3;
    int tid = threadIdx.x;
    int c0 = (tid & 15) * 4, r0 = (tid >> 4) * 4;
    float acc[4][4] = {};
    for (int kt = 0; kt < 8; ++kt) {
        if (kt) __syncthreads();
        for (int l = tid; l < 64 * 16; l += 256) {
            int r = l >> 4, c4 = (l & 15) * 4;
            int grow = rt * 64 + r;
            float4 v = *(const float4*)&x[grow * DD + kt * 64 + c4];
            al[r * 65 + c4] = v.x; al[r * 65 + c4 + 1] = v.y;
            al[r * 65 + c4 + 2] = v.z; al[r * 65 + c4 + 3] = v.w;
            float4 u = *(const float4*)&gw[(it * 64 + r) * DD + kt * 64 + c4];
            bl[r * 65 + c4] = u.x; bl[r * 65 + c4 + 1] = u.y;
            bl[r * 65 + c4 + 2] = u.z; bl[r * 65 + c4 + 3] = u.w;
        }
        __syncthreads();
        for (int kk = 0; kk < 64; ++kk) {
            float af[4], bf[4];
#pragma unroll
            for (int q = 0; q < 4; ++q) { af[q] = al[(r0 + q) * 65 + kk]; bf[q] = bl[(c0 + q) * 65 + kk]; }
#pragma unroll
            for (int q = 0; q < 4; ++q)
#pragma unroll
                for (int w2 = 0; w2 < 4; ++w2) acc[q][w2] += af[q] * bf[w2];
        }
    }
#pragma unroll
    for (int q = 0; q < 4; ++q) {
        int grow = rt * 64 + r0 + q;
        float4 cur = *(float4*)&out[grow * DD + it * 64 + c0];
        float z0 = acc[q][0] + gb[it * 64 + c0 + 0];
        float z1 = acc[q][1] + gb[it * 64 + c0 + 1];
        float z2 = acc[q][2] + gb[it * 64 + c0 + 2];
        float z3 = acc[q][3] + gb[it * 64 + c0 + 3];
        cur.x *= 1.f / (1.f + expf(-z0));
        cur.y *= 1.f / (1.f + expf(-z1));
        cur.z *= 1.f / (1.f + expf(-z2));
        cur.w *= 1.f / (1.f + expf(-z3));
        *(float4*)&out[grow * DD + it * 64 + c0] = cur;
    }
}

extern "C" void kernel_launch(void* const* d_in, const int* in_sizes, int n_in,
                              void* d_out, int out_size, void* d_ws, size_t ws_size,
                              hipStream_t stream) {
    const float* x   = (const float*)d_in[0];
    const float* Wc0 = (const float*)d_in[1];
    const float* Wb  = (const float*)d_in[2];
    const float* gw  = (const float*)d_in[3];
    const float* gb  = (const float*)d_in[4];
    float* out  = (float*)d_out;
    float* outW = out + BB * TT * DD;

    float* ws = (float*)d_ws;
    float* A  = ws + OFF_A;
    float* CU = ws + OFF_CU;
    float* G  = ws + OFF_G;
    float* P  = ws + OFF_P;
    float* BV = ws + OFF_BV;
    float* W  = ws + OFF_W;
    float* WS = ws + OFF_WS;
    float* S  = ws + OFF_S;
    unsigned int* bar = (unsigned int*)(ws + OFF_BAR);

    // barrier counter must start at 0 (ws is poisoned between runs)
    hipMemsetAsync((void*)bar, 0, 256, stream);

    tm_seq<<<256, 256, 0, stream>>>(x, Wc0, Wb, A, CU, G, P, BV, W, WS, S, out, outW, bar);
    tm_gate<<<512 * 8, 256, 0, stream>>>(x, gw, gb, out);
}

// Round 4
// 16011.833 us; speedup vs baseline: 1.0827x; 1.0827x over previous
//
#include <hip/hip_runtime.h>
#include <math.h>

#define BB 8
#define TT 4096
#define DD 512
constexpr float LRF = 0.01f;

// ---------------- workspace layout (floats) ----------------
// A  : [4096][512]   CU : [4096][512]   G : [16][256][256]
// P  : [256][512]    W : [512][512]
// WS : [16][512][512] S : [16][2048][256]  BAR: slots[256]*32u + flag
#define OFF_A  0
#define OFF_CU 2097152
#define OFF_G  4194304
#define OFF_P  5242880
#define OFF_W  5406720
#define OFF_WS 5668864
#define OFF_S  9863168
#define OFF_BAR 18251776
// BAR area: 256 slots * 32 uints (128B apart) + flag = 8224 uints

// ---------- software grid barrier: per-block slots + broadcast flag ----------
// Arrival: block b release-stores gen to its own slot (parallel, no RMW).
// Master (block 0): threads 1..255 poll slots[1..255]; then one release-store
// to flag. Everyone polls flag relaxed, then ONE acquire fence (__threadfence).
// Release(wb) always precedes acquire(inv) -> no dirty-line loss.
__device__ __forceinline__ void gbar(unsigned int* bar, unsigned int gen) {
    __syncthreads();
    const int bid = blockIdx.x, tid = threadIdx.x;
    unsigned int* flag = bar + 8192;
    if (bid == 0) {
        if (tid >= 1) {
            unsigned int* slot = bar + tid * 32;
            while (__hip_atomic_load(slot, __ATOMIC_RELAXED, __HIP_MEMORY_SCOPE_AGENT) < gen)
                __builtin_amdgcn_s_sleep(1);
        }
        __syncthreads();
        if (tid == 0) {
            __hip_atomic_store(flag, gen, __ATOMIC_RELEASE, __HIP_MEMORY_SCOPE_AGENT);
            __threadfence();   // acquire side: invalidate stale L1/L2 lines
        }
    } else {
        if (tid == 0) {
            __hip_atomic_store(bar + bid * 32, gen, __ATOMIC_RELEASE, __HIP_MEMORY_SCOPE_AGENT);
            while (__hip_atomic_load(flag, __ATOMIC_RELAXED, __HIP_MEMORY_SCOPE_AGENT) < gen)
                __builtin_amdgcn_s_sleep(1);
            __threadfence();   // acquire side: invalidate stale L1/L2 lines
        }
    }
    __syncthreads();
}

// ---------- shared 64x64 tile helpers (pad-65 LDS, 4x4 micro) ----------
__device__ __forceinline__ void mm_stage(const float* ga, const float* gbm,
                                         float* L0, float* L1, int tid) {
    for (int l = tid; l < 64 * 16; l += 256) {
        int r = l >> 4, c4 = (l & 15) * 4;
        float4 v = *(const float4*)&ga[r * DD + c4];
        L0[r * 65 + c4] = v.x; L0[r * 65 + c4 + 1] = v.y;
        L0[r * 65 + c4 + 2] = v.z; L0[r * 65 + c4 + 3] = v.w;
        float4 u = *(const float4*)&gbm[r * DD + c4];
        L1[r * 65 + c4] = u.x; L1[r * 65 + c4 + 1] = u.y;
        L1[r * 65 + c4 + 2] = u.z; L1[r * 65 + c4 + 3] = u.w;
    }
}

// C[64][64] += A_tile[64][512] * B_tile[64][512]^T
__device__ __forceinline__ void mm_tile(const float* ga, const float* gbm,
                                        float* L0, float* L1, int tid, int r0, int c0,
                                        float acc[4][4]) {
    for (int kt = 0; kt < 8; ++kt) {
        __syncthreads();
        mm_stage(ga + kt * 64, gbm + kt * 64, L0, L1, tid);
        __syncthreads();
        for (int kk = 0; kk < 64; ++kk) {
            float af[4], bf[4];
#pragma unroll
            for (int q = 0; q < 4; ++q) { af[q] = L0[(r0 + q) * 65 + kk]; bf[q] = L1[(c0 + q) * 65 + kk]; }
#pragma unroll
            for (int q = 0; q < 4; ++q)
#pragma unroll
                for (int w2 = 0; w2 < 4; ++w2) acc[q][w2] += af[q] * bf[w2];
        }
    }
}

// out[row][i] += LR * sum_{s<tloc} S[p][rloc][s] * cu[p*256+s][i]   (one 64x64 tile)
__device__ __forceinline__ void apply_tile(const float* S, const float* CU, float* out,
                                           int t_, float* L0, float* L1, int tid, int r0, int c0) {
    int it = t_ & 7, rt = (t_ >> 3) & 31, p = t_ >> 8;
    float acc[4][4] = {};
    for (int kt = 0; kt < 4; ++kt) {
        __syncthreads();
        for (int l = tid; l < 64 * 16; l += 256) {
            int r = l >> 4, c4 = (l & 15) * 4;
            int rloc = rt * 64 + r;
            int tq = rloc & 255;
            float4 v = *(const float4*)&S[(p * 2048 + rloc) * 256 + kt * 64 + c4];
            int sb = kt * 64 + c4;
            L0[r * 65 + c4]     = (sb + 0 < tq) ? v.x : 0.f;
            L0[r * 65 + c4 + 1] = (sb + 1 < tq) ? v.y : 0.f;
            L0[r * 65 + c4 + 2] = (sb + 2 < tq) ? v.z : 0.f;
            L0[r * 65 + c4 + 3] = (sb + 3 < tq) ? v.w : 0.f;
            float4 u = *(const float4*)&CU[(p * 256 + kt * 64 + r) * DD + it * 64 + c4];
            L1[r * 65 + c4] = u.x; L1[r * 65 + c4 + 1] = u.y;
            L1[r * 65 + c4 + 2] = u.z; L1[r * 65 + c4 + 3] = u.w;
        }
        __syncthreads();
        for (int kk = 0; kk < 64; ++kk) {
            float af[4], bf[4];
#pragma unroll
            for (int q = 0; q < 4; ++q) { af[q] = L0[(r0 + q) * 65 + kk]; bf[q] = L1[kk * 65 + c0 + q]; }
#pragma unroll
            for (int q = 0; q < 4; ++q)
#pragma unroll
                for (int w2 = 0; w2 < 4; ++w2) acc[q][w2] += af[q] * bf[w2];
        }
    }
#pragma unroll
    for (int q = 0; q < 4; ++q) {
        int rloc = rt * 64 + r0 + q;
        int grow = ((rloc >> 8) * TT) + p * 256 + (rloc & 255);
        float4 cur = *(float4*)&out[grow * DD + it * 64 + c0];
        cur.x += LRF * acc[q][0]; cur.y += LRF * acc[q][1];
        cur.z += LRF * acc[q][2]; cur.w += LRF * acc[q][3];
        *(float4*)&out[grow * DD + it * 64 + c0] = cur;
    }
}

// merged corr+scan for chunk k=4p+j, ONE block (thread = dims d, d+256).
// corr: acc[t] = P[j64+t][d] - LR*sum_{s<j*64} G[s][j64+t]*CU[p256+s][d]
//   (CU chunks were written by THIS block in earlier phases -> same-CU coherent)
// scan: 64 sequential normalize+update steps, writes CU chunk k.
__device__ void corr_scan(const float* __restrict__ Pm, const float* __restrict__ G,
                          float* __restrict__ CU, int p, int j, float* lds, int tid) {
    float* gl = lds;            // 64*64
    float* part = lds + 4096;   // [2][4]
    int wid = tid >> 6, lane = tid & 63;
    const float* Gp = G + p * 65536;
    float acc0[64], acc1[64];
#pragma unroll
    for (int t = 0; t < 64; ++t) {
        acc0[t] = Pm[(j * 64 + t) * DD + tid];
        acc1[t] = Pm[(j * 64 + t) * DD + tid + 256];
    }
    for (int kb = 0; kb < j; ++kb) {
        __syncthreads();
        for (int l = tid; l < 64 * 16; l += 256) {
            int r = l >> 4, c4 = (l & 15) * 4;
            float4 v = *(const float4*)&Gp[(kb * 64 + r) * 256 + j * 64 + c4];
            *(float4*)&gl[r * 64 + c4] = v;
        }
        __syncthreads();
        const float* cub = CU + (p * 256 + kb * 64) * DD;
        for (int s = 0; s < 64; ++s) {
            float cw0 = -LRF * cub[s * DD + tid];
            float cw1 = -LRF * cub[s * DD + tid + 256];
#pragma unroll
            for (int t4 = 0; t4 < 64; t4 += 4) {
                float4 g4 = *(const float4*)&gl[s * 64 + t4];
                acc0[t4]     += g4.x * cw0; acc1[t4]     += g4.x * cw1;
                acc0[t4 + 1] += g4.y * cw0; acc1[t4 + 1] += g4.y * cw1;
                acc0[t4 + 2] += g4.z * cw0; acc1[t4 + 2] += g4.z * cw1;
                acc0[t4 + 3] += g4.w * cw0; acc1[t4 + 3] += g4.w * cw1;
            }
        }
    }
    // stage diagonal Gram block for the scan
    __syncthreads();
    for (int l = tid; l < 64 * 16; l += 256) {
        int r = l >> 4, c4 = (l & 15) * 4;
        float4 v = *(const float4*)&Gp[(j * 64 + r) * 256 + j * 64 + c4];
        *(float4*)&gl[r * 64 + c4] = v;
    }
    __syncthreads();
    float* cup = CU + (p * 256 + j * 64) * DD;
#pragma unroll
    for (int s = 0; s < 64; ++s) {
        float u0 = acc0[s], u1 = acc1[s];
        float v = u0 * u0 + u1 * u1;
#pragma unroll
        for (int off = 32; off > 0; off >>= 1) v += __shfl_xor(v, off, 64);
        if (lane == 0) part[(s & 1) * 4 + wid] = v;
        __syncthreads();
        float n2u = part[(s & 1) * 4 + 0] + part[(s & 1) * 4 + 1]
                  + part[(s & 1) * 4 + 2] + part[(s & 1) * 4 + 3];
        float n2 = n2u * gl[s * 64 + s];                      // ||u||^2 * ||a||^2
        float cs = (n2 > 0.25f) ? 0.5f * rsqrtf(n2) : 1.0f;  // min(1, CLIP/n)
        cup[s * DD + tid] = cs * u0;
        cup[s * DD + tid + 256] = cs * u1;
        float w0 = (LRF * cs) * u0, w1 = (LRF * cs) * u1;
        int t0 = s + 1;
#pragma unroll
        for (; t0 < 64 && (t0 & 3); ++t0) {
            float g = gl[s * 64 + t0];
            acc0[t0] -= g * w0; acc1[t0] -= g * w1;
        }
#pragma unroll
        for (; t0 < 64; t0 += 4) {
            float4 g4 = *(const float4*)&gl[s * 64 + t0];
            acc0[t0]     -= g4.x * w0; acc1[t0]     -= g4.x * w1;
            acc0[t0 + 1] -= g4.y * w0; acc1[t0 + 1] -= g4.y * w1;
            acc0[t0 + 2] -= g4.z * w0; acc1[t0 + 2] -= g4.z * w1;
            acc0[t0 + 3] -= g4.w * w0; acc1[t0 + 3] -= g4.w * w1;
        }
    }
}

// =====================================================================
// ONE kernel (regular launch, 256 blocks x 256 threads, all resident).
// 97 software barriers. Chunk-phase (k=4p+j) roles:
//   blk 0      : corr+scan (merged)
//   blk 1-32   : score tiles (32/phase x 64 = 2048)
//   blk 33-96  : mem tiles   (64/phase x 64 = 4096; phase k carries sc p)
//   blk 97-160 : apply tiles for superchunk p-1 (64/phase x 4 = 256)
// Then per superchunk: wupd phase (all blocks), P phase (blocks 0-31).
// Tail: 256 apply tiles for superchunk 15.
// =====================================================================
__global__ __launch_bounds__(256) void tm_seq(
    const float* __restrict__ x, const float* __restrict__ Wc0, const float* __restrict__ Wb,
    float* A, float* CU, float* G, float* P, float* W, float* WS, float* S,
    float* out, float* outW, unsigned int* bar)
{
    const int bid = blockIdx.x;
    const int tid = threadIdx.x;
    const int c0 = (tid & 15) * 4, r0 = (tid >> 4) * 4;
    unsigned int gen = 0;

    __shared__ float lds[2 * 64 * 65 + 16];
    float* L0 = lds;
    float* L1 = lds + 64 * 65;

    // ---- phase 0: batch-mean of x + W init/snapshot(0) ----
    for (int it = 0; it < 32; ++it) {
        int idx = (bid * 32 + it) * 256 + tid;
        float s = 0.f;
#pragma unroll
        for (int b = 0; b < BB; ++b) s += x[b * (TT * DD) + idx];
        A[idx] = s * 0.125f;
    }
    for (int it = 0; it < 4; ++it) {
        int idx = (bid * 4 + it) * 256 + tid;
        float v = Wb[idx] + Wc0[idx];
        W[idx] = v; WS[idx] = v;
    }
    gbar(bar, ++gen);

    // ---- phase 1: Gram diag tiles (all 256 blocks) + P(0) (blocks 0..31) ----
    {
        int p = bid >> 4, ts = (bid >> 2) & 3, ttl = bid & 3;
        float acc[4][4] = {};
        mm_tile(A + (p * 256 + ts * 64) * DD, A + (p * 256 + ttl * 64) * DD,
                L0, L1, tid, r0, c0, acc);
#pragma unroll
        for (int q = 0; q < 4; ++q)
            *(float4*)&G[p * 65536 + (ts * 64 + r0 + q) * 256 + ttl * 64 + c0] =
                make_float4(acc[q][0], acc[q][1], acc[q][2], acc[q][3]);
    }
    if (bid < 32) {
        int bt = bid & 3, bi = bid >> 2;
        float acc[4][4] = {};
        mm_tile(A + bt * 64 * DD, W + bi * 64 * DD, L0, L1, tid, r0, c0, acc);
#pragma unroll
        for (int q = 0; q < 4; ++q) {
            float4 av = *(const float4*)&A[(bt * 64 + r0 + q) * DD + bi * 64 + c0];
            *(float4*)&P[(bt * 64 + r0 + q) * DD + bi * 64 + c0] =
                make_float4(av.x - acc[q][0], av.y - acc[q][1], av.z - acc[q][2], av.w - acc[q][3]);
        }
    }
    gbar(bar, ++gen);

    // ---- main sequential loop over 16 superchunks ----
    for (int p = 0; p < 16; ++p) {
        for (int j = 0; j < 4; ++j) {
            int k = p * 4 + j;
            if (bid == 0) {
                corr_scan(P, G, CU, p, j, lds, tid);
            } else if (bid < 33) {
                // score tile: needs only A
                int t_ = k * 32 + (bid - 1);
                int st = t_ & 3, rt = (t_ >> 2) & 31, ps = t_ >> 7;
                int growbase = (rt >> 2) * TT + ps * 256 + (rt & 3) * 64;
                float acc[4][4] = {};
                mm_tile(x + growbase * DD, A + (ps * 256 + st * 64) * DD,
                        L0, L1, tid, r0, c0, acc);
#pragma unroll
                for (int q = 0; q < 4; ++q)
                    *(float4*)&S[(ps * 2048 + rt * 64 + r0 + q) * 256 + st * 64 + c0] =
                        make_float4(acc[q][0], acc[q][1], acc[q][2], acc[q][3]);
            } else if (bid < 97) {
                // mem tile: phase k carries exactly superchunk p -> WS[p] ready
                int t_ = k * 64 + (bid - 33);
                int pm = t_ >> 8, rem = t_ & 255, rt = rem >> 3, itile = rem & 7;
                int growbase = (rt >> 2) * TT + pm * 256 + (rt & 3) * 64;
                float acc[4][4] = {};
                mm_tile(x + growbase * DD, WS + pm * DD * DD + itile * 64 * DD,
                        L0, L1, tid, r0, c0, acc);
#pragma unroll
                for (int q = 0; q < 4; ++q)
                    *(float4*)&out[(growbase + r0 + q) * DD + itile * 64 + c0] =
                        make_float4(acc[q][0], acc[q][1], acc[q][2], acc[q][3]);
            } else if (bid < 161 && p > 0) {
                // apply tiles for superchunk p-1 (CU, S, out rows all >=1 barrier old)
                int t_ = (p - 1) * 256 + j * 64 + (bid - 97);
                apply_tile(S, CU, out, t_, L0, L1, tid, r0, c0);
            }
            gbar(bar, ++gen);
        }

        // ======== W update (+snapshot p+1 / final outW) : all 256 blocks ========
        for (int it = 0; it < 4; ++it) {
            int idx = (bid * 4 + it) * 256 + tid;
            int i = idx >> 9, jj = idx & 511;
            const float* cb = CU + p * 256 * DD + i;
            const float* ab = A + p * 256 * DD + jj;
            float s = 0.f;
#pragma unroll 8
            for (int r = 0; r < 256; ++r) s += cb[r * DD] * ab[r * DD];
            float w = W[idx] + LRF * s;
            W[idx] = w;
            if (p < 15) WS[(p + 1) * DD * DD + idx] = w;
            else outW[idx] = w - Wb[idx];
        }
        gbar(bar, ++gen);

        // ======== next P : blocks 0..31 ========
        if (p < 15) {
            if (bid < 32) {
                int bt = bid & 3, bi = bid >> 2;
                float acc[4][4] = {};
                mm_tile(A + ((p + 1) * 256 + bt * 64) * DD, W + bi * 64 * DD,
                        L0, L1, tid, r0, c0, acc);
#pragma unroll
                for (int q = 0; q < 4; ++q) {
                    float4 av = *(const float4*)&A[((p + 1) * 256 + bt * 64 + r0 + q) * DD + bi * 64 + c0];
                    *(float4*)&P[(bt * 64 + r0 + q) * DD + bi * 64 + c0] =
                        make_float4(av.x - acc[q][0], av.y - acc[q][1], av.z - acc[q][2], av.w - acc[q][3]);
                }
            }
            gbar(bar, ++gen);
        }
    }

    // ---- tail: apply tiles for superchunk 15 (one per block) ----
    {
        int t_ = 15 * 256 + bid;
        apply_tile(S, CU, out, t_, L0, L1, tid, r0, c0);
    }
}

// out[row][i] *= sigmoid(x[row] . gate_w[i] + gate_b[i])   (unchanged)
__global__ __launch_bounds__(256) void tm_gate(const float* __restrict__ x, const float* __restrict__ gw,
                                               const float* __restrict__ gb, float* __restrict__ out) {
    __shared__ float al[64 * 65];
    __shared__ float bl[64 * 65];
    int bid = blockIdx.x;
    int it = bid & 7, rt = bid >> 3;
    int tid = threadIdx.x;
    int c0 = (tid & 15) * 4, r0 = (tid >> 4) * 4;
    float acc[4][4] = {};
    for (int kt = 0; kt < 8; ++kt) {
        if (kt) __syncthreads();
        for (int l = tid; l < 64 * 16; l += 256) {
            int r = l >> 4, c4 = (l & 15) * 4;
            int grow = rt * 64 + r;
            float4 v = *(const float4*)&x[grow * DD + kt * 64 + c4];
            al[r * 65 + c4] = v.x; al[r * 65 + c4 + 1] = v.y;
            al[r * 65 + c4 + 2] = v.z; al[r * 65 + c4 + 3] = v.w;
            float4 u = *(const float4*)&gw[(it * 64 + r) * DD + kt * 64 + c4];
            bl[r * 65 + c4] = u.x; bl[r * 65 + c4 + 1] = u.y;
            bl[r * 65 + c4 + 2] = u.z; bl[r * 65 + c4 + 3] = u.w;
        }
        __syncthreads();
        for (int kk = 0; kk < 64; ++kk) {
            float af[4], bf[4];
#pragma unroll
            for (int q = 0; q < 4; ++q) { af[q] = al[(r0 + q) * 65 + kk]; bf[q] = bl[(c0 + q) * 65 + kk]; }
#pragma unroll
            for (int q = 0; q < 4; ++q)
#pragma unroll
                for (int w2 = 0; w2 < 4; ++w2) acc[q][w2] += af[q] * bf[w2];
        }
    }
#pragma unroll
    for (int q = 0; q < 4; ++q) {
        int grow = rt * 64 + r0 + q;
        float4 cur = *(float4*)&out[grow * DD + it * 64 + c0];
        float z0 = acc[q][0] + gb[it * 64 + c0 + 0];
        float z1 = acc[q][1] + gb[it * 64 + c0 + 1];
        float z2 = acc[q][2] + gb[it * 64 + c0 + 2];
        float z3 = acc[q][3] + gb[it * 64 + c0 + 3];
        cur.x *= 1.f / (1.f + expf(-z0));
        cur.y *= 1.f / (1.f + expf(-z1));
        cur.z *= 1.f / (1.f + expf(-z2));
        cur.w *= 1.f / (1.f + expf(-z3));
        *(float4*)&out[grow * DD + it * 64 + c0] = cur;
    }
}

extern "C" void kernel_launch(void* const* d_in, const int* in_sizes, int n_in,
                              void* d_out, int out_size, void* d_ws, size_t ws_size,
                              hipStream_t stream) {
    const float* x   = (const float*)d_in[0];
    const float* Wc0 = (const float*)d_in[1];
    const float* Wb  = (const float*)d_in[2];
    const float* gw  = (const float*)d_in[3];
    const float* gb  = (const float*)d_in[4];
    float* out  = (float*)d_out;
    float* outW = out + BB * TT * DD;

    float* ws = (float*)d_ws;
    float* A  = ws + OFF_A;
    float* CU = ws + OFF_CU;
    float* G  = ws + OFF_G;
    float* P  = ws + OFF_P;
    float* W  = ws + OFF_W;
    float* WS = ws + OFF_WS;
    float* S  = ws + OFF_S;
    unsigned int* bar = (unsigned int*)(ws + OFF_BAR);

    // barrier slots+flag must start at 0 (ws is poisoned between runs)
    (void)hipMemsetAsync((void*)bar, 0, (8192 + 32) * sizeof(unsigned int), stream);

    tm_seq<<<256, 256, 0, stream>>>(x, Wc0, Wb, A, CU, G, P, W, WS, S, out, outW, bar);
    tm_gate<<<512 * 8, 256, 0, stream>>>(x, gw, gb, out);
}

// Round 5
// 11337.262 us; speedup vs baseline: 1.5291x; 1.4123x over previous
//
#include <hip/hip_runtime.h>
#include <math.h>

#define BB 8
#define TT 4096
#define DD 512
constexpr float LRF = 0.01f;

// ---------------- workspace layout (floats) ----------------
// A  : [4096][512]        mean of x over batch
// CU : [4096][512]        c_s * u_s
// G  : [16][256][256]     per-superchunk Gram of A
// P  : [256][512]         A_sc - A_sc @ W(p)^T   (reused per superchunk)
// W  : [512][512]         running W_base + W_c
// WS : [16][512][512]     W snapshots at t = 256*p
// S  : [16][2048][256]    attention scores
#define OFF_A  0
#define OFF_CU 2097152
#define OFF_G  4194304
#define OFF_P  5242880
#define OFF_W  5406720
#define OFF_WS 5668864
#define OFF_S  9863168

__global__ void tm_mean(const float* __restrict__ x, float* __restrict__ a) {
    int idx = blockIdx.x * 256 + threadIdx.x;   // t*D + d
    float s = 0.f;
#pragma unroll
    for (int b = 0; b < BB; ++b) s += x[b * (TT * DD) + idx];
    a[idx] = s * 0.125f;
}

__global__ void tm_init(const float* __restrict__ wb, const float* __restrict__ wc,
                        float* __restrict__ W, float* __restrict__ Wsnap) {
    int idx = blockIdx.x * 256 + threadIdx.x;
    float v = wb[idx] + wc[idx];
    W[idx] = v;
    Wsnap[idx] = v;   // snapshot p=0 (t=0)
}

// full Gram per superchunk: G[p][s][t] = a_{p*256+s} . a_{p*256+t}
__global__ __launch_bounds__(256) void tm_gram(const float* __restrict__ a, float* __restrict__ G) {
    __shared__ float sl[64 * 65];
    __shared__ float tl[64 * 65];
    int bid = blockIdx.x;
    int p = bid >> 4, ts = (bid >> 2) & 3, tt = bid & 3;
    int tid = threadIdx.x;
    int c0 = (tid & 15) * 4, r0 = (tid >> 4) * 4;
    float acc[4][4] = {};
    for (int kt = 0; kt < 8; ++kt) {
        if (kt) __syncthreads();
        for (int l = tid; l < 64 * 16; l += 256) {
            int r = l >> 4, c4 = (l & 15) * 4;
            float4 v = *(const float4*)&a[(p * 256 + ts * 64 + r) * DD + kt * 64 + c4];
            sl[r * 65 + c4] = v.x; sl[r * 65 + c4 + 1] = v.y;
            sl[r * 65 + c4 + 2] = v.z; sl[r * 65 + c4 + 3] = v.w;
            float4 u = *(const float4*)&a[(p * 256 + tt * 64 + r) * DD + kt * 64 + c4];
            tl[r * 65 + c4] = u.x; tl[r * 65 + c4 + 1] = u.y;
            tl[r * 65 + c4 + 2] = u.z; tl[r * 65 + c4 + 3] = u.w;
        }
        __syncthreads();
        for (int kk = 0; kk < 64; ++kk) {
            float as[4], at[4];
#pragma unroll
            for (int q = 0; q < 4; ++q) { as[q] = sl[(r0 + q) * 65 + kk]; at[q] = tl[(c0 + q) * 65 + kk]; }
#pragma unroll
            for (int q = 0; q < 4; ++q)
#pragma unroll
                for (int w2 = 0; w2 < 4; ++w2) acc[q][w2] += as[q] * at[w2];
        }
    }
#pragma unroll
    for (int q = 0; q < 4; ++q) {
        float4 v = make_float4(acc[q][0], acc[q][1], acc[q][2], acc[q][3]);
        *(float4*)&G[p * 65536 + (ts * 64 + r0 + q) * 256 + tt * 64 + c0] = v;
    }
}

// P[t][i] = a[p*256+t][i] - sum_j W[i][j] a[p*256+t][j];  grid 32 (bt 0..3, bi 0..7)
__global__ __launch_bounds__(256) void tm_P(const float* __restrict__ a, const float* __restrict__ W,
                                            float* __restrict__ P, int p) {
    __shared__ float al[64 * 65];
    __shared__ float wl[64 * 65];
    int bid = blockIdx.x;
    int bt = bid & 3, bi = bid >> 2;
    int tid = threadIdx.x;
    int c0 = (tid & 15) * 4, r0 = (tid >> 4) * 4;
    float acc[4][4] = {};
    for (int kt = 0; kt < 8; ++kt) {
        if (kt) __syncthreads();
        for (int l = tid; l < 64 * 16; l += 256) {
            int r = l >> 4, c4 = (l & 15) * 4;
            float4 v = *(const float4*)&a[(p * 256 + bt * 64 + r) * DD + kt * 64 + c4];
            al[r * 65 + c4] = v.x; al[r * 65 + c4 + 1] = v.y;
            al[r * 65 + c4 + 2] = v.z; al[r * 65 + c4 + 3] = v.w;
            float4 u = *(const float4*)&W[(bi * 64 + r) * DD + kt * 64 + c4];
            wl[r * 65 + c4] = u.x; wl[r * 65 + c4 + 1] = u.y;
            wl[r * 65 + c4 + 2] = u.z; wl[r * 65 + c4 + 3] = u.w;
        }
        __syncthreads();
        for (int kk = 0; kk < 64; ++kk) {
            float af[4], bf[4];
#pragma unroll
            for (int q = 0; q < 4; ++q) { af[q] = al[(r0 + q) * 65 + kk]; bf[q] = wl[(c0 + q) * 65 + kk]; }
#pragma unroll
            for (int q = 0; q < 4; ++q)
#pragma unroll
                for (int w2 = 0; w2 < 4; ++w2) acc[q][w2] += af[q] * bf[w2];
        }
    }
#pragma unroll
    for (int q = 0; q < 4; ++q) {
        float4 av = *(const float4*)&a[(p * 256 + bt * 64 + r0 + q) * DD + bi * 64 + c0];
        float4 v = make_float4(av.x - acc[q][0], av.y - acc[q][1],
                               av.z - acc[q][2], av.w - acc[q][3]);
        *(float4*)&P[(bt * 64 + r0 + q) * DD + bi * 64 + c0] = v;
    }
}

// merged corr+scan for chunk j of superchunk p, ONE block (thread = dims d, d+256).
// corr: acc[t] = P[j64+t][d] - LR*sum_{s<j*64} G[s][j64+t]*CU[p256+s][d]
//   CU rows read here were written by THIS block (same thread<->address map) in
//   earlier j iterations -> program order + waitcnt suffice, no fence needed.
// scan: 64 sequential normalize+update steps, writes CU chunk.
__device__ void corr_scan(const float* __restrict__ Pm, const float* __restrict__ G,
                          float* __restrict__ CU, int p, int j, float* lds, int tid) {
    float* gl = lds;            // 64*64
    float* part = lds + 4096;   // [2][4]
    int wid = tid >> 6, lane = tid & 63;
    const float* Gp = G + p * 65536;
    float acc0[64], acc1[64];
#pragma unroll
    for (int t = 0; t < 64; ++t) {
        acc0[t] = Pm[(j * 64 + t) * DD + tid];
        acc1[t] = Pm[(j * 64 + t) * DD + tid + 256];
    }
    for (int kb = 0; kb < j; ++kb) {
        __syncthreads();
        for (int l = tid; l < 64 * 16; l += 256) {
            int r = l >> 4, c4 = (l & 15) * 4;
            float4 v = *(const float4*)&Gp[(kb * 64 + r) * 256 + j * 64 + c4];
            *(float4*)&gl[r * 64 + c4] = v;
        }
        __syncthreads();
        const float* cub = CU + (p * 256 + kb * 64) * DD;
        for (int s = 0; s < 64; ++s) {
            float cw0 = -LRF * cub[s * DD + tid];
            float cw1 = -LRF * cub[s * DD + tid + 256];
#pragma unroll
            for (int t4 = 0; t4 < 64; t4 += 4) {
                float4 g4 = *(const float4*)&gl[s * 64 + t4];
                acc0[t4]     += g4.x * cw0; acc1[t4]     += g4.x * cw1;
                acc0[t4 + 1] += g4.y * cw0; acc1[t4 + 1] += g4.y * cw1;
                acc0[t4 + 2] += g4.z * cw0; acc1[t4 + 2] += g4.z * cw1;
                acc0[t4 + 3] += g4.w * cw0; acc1[t4 + 3] += g4.w * cw1;
            }
        }
    }
    // stage diagonal Gram block for the scan
    __syncthreads();
    for (int l = tid; l < 64 * 16; l += 256) {
        int r = l >> 4, c4 = (l & 15) * 4;
        float4 v = *(const float4*)&Gp[(j * 64 + r) * 256 + j * 64 + c4];
        *(float4*)&gl[r * 64 + c4] = v;
    }
    __syncthreads();
    float* cup = CU + (p * 256 + j * 64) * DD;
#pragma unroll
    for (int s = 0; s < 64; ++s) {
        float u0 = acc0[s], u1 = acc1[s];
        float v = u0 * u0 + u1 * u1;
#pragma unroll
        for (int off = 32; off > 0; off >>= 1) v += __shfl_xor(v, off, 64);
        if (lane == 0) part[(s & 1) * 4 + wid] = v;
        __syncthreads();
        float n2u = part[(s & 1) * 4 + 0] + part[(s & 1) * 4 + 1]
                  + part[(s & 1) * 4 + 2] + part[(s & 1) * 4 + 3];
        float n2 = n2u * gl[s * 64 + s];                      // ||u||^2 * ||a||^2
        float cs = (n2 > 0.25f) ? 0.5f * rsqrtf(n2) : 1.0f;  // min(1, CLIP/n)
        cup[s * DD + tid] = cs * u0;
        cup[s * DD + tid + 256] = cs * u1;
        float w0 = (LRF * cs) * u0, w1 = (LRF * cs) * u1;
        int t0 = s + 1;
#pragma unroll
        for (; t0 < 64 && (t0 & 3); ++t0) {
            float g = gl[s * 64 + t0];
            acc0[t0] -= g * w0; acc1[t0] -= g * w1;
        }
#pragma unroll
        for (; t0 < 64; t0 += 4) {
            float4 g4 = *(const float4*)&gl[s * 64 + t0];
            acc0[t0]     -= g4.x * w0; acc1[t0]     -= g4.x * w1;
            acc0[t0 + 1] -= g4.y * w0; acc1[t0 + 1] -= g4.y * w1;
            acc0[t0 + 2] -= g4.z * w0; acc1[t0 + 2] -= g4.z * w1;
            acc0[t0 + 3] -= g4.w * w0; acc1[t0 + 3] -= g4.w * w1;
        }
    }
}

// all 4 chunks of superchunk p in ONE launch (1 block, 256 threads)
__global__ __launch_bounds__(256) void tm_scanall(const float* __restrict__ P,
                                                  const float* __restrict__ G,
                                                  float* __restrict__ CU, int p) {
    __shared__ float lds[64 * 64 + 16];
    for (int j = 0; j < 4; ++j)
        corr_scan(P, G, CU, p, j, lds, threadIdx.x);
}

// W += LR * sum_{r in sc p} cu_r (x) a_r  (rank-256); optional snapshot / final output
__global__ void tm_wupd(const float* __restrict__ a, const float* __restrict__ cu,
                        float* __restrict__ W, float* __restrict__ Wsnap,
                        const float* __restrict__ wb, float* __restrict__ outW,
                        int p, int snap_p, int is_final) {
    int idx = blockIdx.x * 256 + threadIdx.x;
    int i = idx >> 9, jj = idx & 511;
    const float* cb = cu + p * 256 * DD + i;
    const float* ab = a + p * 256 * DD + jj;
    float s = 0.f;
#pragma unroll 8
    for (int r = 0; r < 256; ++r) s += cb[r * DD] * ab[r * DD];
    float w = W[idx] + LRF * s;
    W[idx] = w;
    if (snap_p >= 0) Wsnap[snap_p * DD * DD + idx] = w;
    if (is_final) outW[idx] = w - wb[idx];
}

// ---------------- phase 3 (parallel output) ----------------

// S[p][rloc][s] = x[row] . a[p*256+s]
__global__ __launch_bounds__(256) void tm_score(const float* __restrict__ x, const float* __restrict__ a,
                                                float* __restrict__ S) {
    __shared__ float al[64 * 65];
    __shared__ float bl[64 * 65];
    int bid = blockIdx.x;
    int st = bid & 3, rt = (bid >> 2) & 31, p = bid >> 7;
    int tid = threadIdx.x;
    int c0 = (tid & 15) * 4, r0 = (tid >> 4) * 4;
    float acc[4][4] = {};
    for (int kt = 0; kt < 8; ++kt) {
        if (kt) __syncthreads();
        for (int l = tid; l < 64 * 16; l += 256) {
            int r = l >> 4, c4 = (l & 15) * 4;
            int rloc = rt * 64 + r;
            int grow = ((rloc >> 8) * TT) + p * 256 + (rloc & 255);
            float4 v = *(const float4*)&x[grow * DD + kt * 64 + c4];
            al[r * 65 + c4] = v.x; al[r * 65 + c4 + 1] = v.y;
            al[r * 65 + c4 + 2] = v.z; al[r * 65 + c4 + 3] = v.w;
            float4 u = *(const float4*)&a[(p * 256 + st * 64 + r) * DD + kt * 64 + c4];
            bl[r * 65 + c4] = u.x; bl[r * 65 + c4 + 1] = u.y;
            bl[r * 65 + c4 + 2] = u.z; bl[r * 65 + c4 + 3] = u.w;
        }
        __syncthreads();
        for (int kk = 0; kk < 64; ++kk) {
            float af[4], bf[4];
#pragma unroll
            for (int q = 0; q < 4; ++q) { af[q] = al[(r0 + q) * 65 + kk]; bf[q] = bl[(c0 + q) * 65 + kk]; }
#pragma unroll
            for (int q = 0; q < 4; ++q)
#pragma unroll
                for (int w2 = 0; w2 < 4; ++w2) acc[q][w2] += af[q] * bf[w2];
        }
    }
#pragma unroll
    for (int q = 0; q < 4; ++q) {
        int rloc = rt * 64 + r0 + q;
        float4 v = make_float4(acc[q][0], acc[q][1], acc[q][2], acc[q][3]);
        *(float4*)&S[(p * 2048 + rloc) * 256 + st * 64 + c0] = v;
    }
}

// FUSED mem+apply+gate per 64x64 out tile:
// out[row][i] = sigmoid(x.gw[i]+gb[i]) * ( x.WS[p][i] + LR*sum_{s<tloc} S*cu )
// grid 4096: p = bid>>8, rem=bid&255, rt=rem>>3, it=rem&7
__global__ __launch_bounds__(256) void tm_fused(const float* __restrict__ x, const float* __restrict__ Wsnap,
                                                const float* __restrict__ S, const float* __restrict__ cu,
                                                const float* __restrict__ gw, const float* __restrict__ gb,
                                                float* __restrict__ out) {
    __shared__ float al[64 * 65];
    __shared__ float bl[64 * 65];
    int bid = blockIdx.x;
    int p = bid >> 8, rem = bid & 255, rt = rem >> 3, it = rem & 7;
    int tid = threadIdx.x;
    int c0 = (tid & 15) * 4, r0 = (tid >> 4) * 4;
    // x rows for this tile are contiguous: rloc>>8 constant over the 64 rows
    int growbase = (rt >> 2) * TT + p * 256 + (rt & 3) * 64;
    const float* xb = x + growbase * DD;
    const float* Wp = Wsnap + p * DD * DD + it * 64 * DD;
    const float* gwp = gw + it * 64 * DD;

    float accM[4][4] = {};   // mem:  x . WS^T
    float accG[4][4] = {};   // gate: x . gw^T
    float accA[4][4] = {};   // apply: masked(S) . cu

    // pass 1: mem + gate share staged x tile (stage x once, both B operands)
    for (int kt = 0; kt < 8; ++kt) {
        if (kt) __syncthreads();
        for (int l = tid; l < 64 * 16; l += 256) {
            int r = l >> 4, c4 = (l & 15) * 4;
            float4 v = *(const float4*)&xb[r * DD + kt * 64 + c4];
            al[r * 65 + c4] = v.x; al[r * 65 + c4 + 1] = v.y;
            al[r * 65 + c4 + 2] = v.z; al[r * 65 + c4 + 3] = v.w;
            float4 u = *(const float4*)&Wp[r * DD + kt * 64 + c4];
            bl[r * 65 + c4] = u.x; bl[r * 65 + c4 + 1] = u.y;
            bl[r * 65 + c4 + 2] = u.z; bl[r * 65 + c4 + 3] = u.w;
        }
        __syncthreads();
        for (int kk = 0; kk < 64; ++kk) {
            float af[4], bf[4];
#pragma unroll
            for (int q = 0; q < 4; ++q) { af[q] = al[(r0 + q) * 65 + kk]; bf[q] = bl[(c0 + q) * 65 + kk]; }
#pragma unroll
            for (int q = 0; q < 4; ++q)
#pragma unroll
                for (int w2 = 0; w2 < 4; ++w2) accM[q][w2] += af[q] * bf[w2];
        }
        __syncthreads();
        // restage B <- gw tile (x tile al stays valid)
        for (int l = tid; l < 64 * 16; l += 256) {
            int r = l >> 4, c4 = (l & 15) * 4;
            float4 u = *(const float4*)&gwp[r * DD + kt * 64 + c4];
            bl[r * 65 + c4] = u.x; bl[r * 65 + c4 + 1] = u.y;
            bl[r * 65 + c4 + 2] = u.z; bl[r * 65 + c4 + 3] = u.w;
        }
        __syncthreads();
        for (int kk = 0; kk < 64; ++kk) {
            float af[4], bf[4];
#pragma unroll
            for (int q = 0; q < 4; ++q) { af[q] = al[(r0 + q) * 65 + kk]; bf[q] = bl[(c0 + q) * 65 + kk]; }
#pragma unroll
            for (int q = 0; q < 4; ++q)
#pragma unroll
                for (int w2 = 0; w2 < 4; ++w2) accG[q][w2] += af[q] * bf[w2];
        }
    }

    // pass 2: apply (K = 256, causal-masked S)
    for (int kt = 0; kt < 4; ++kt) {
        __syncthreads();
        for (int l = tid; l < 64 * 16; l += 256) {
            int r = l >> 4, c4 = (l & 15) * 4;
            int rloc = rt * 64 + r;
            int tq = rloc & 255;
            float4 v = *(const float4*)&S[(p * 2048 + rloc) * 256 + kt * 64 + c4];
            int sb = kt * 64 + c4;
            al[r * 65 + c4]     = (sb + 0 < tq) ? v.x : 0.f;
            al[r * 65 + c4 + 1] = (sb + 1 < tq) ? v.y : 0.f;
            al[r * 65 + c4 + 2] = (sb + 2 < tq) ? v.z : 0.f;
            al[r * 65 + c4 + 3] = (sb + 3 < tq) ? v.w : 0.f;
            float4 u = *(const float4*)&cu[(p * 256 + kt * 64 + r) * DD + it * 64 + c4];
            bl[r * 65 + c4] = u.x; bl[r * 65 + c4 + 1] = u.y;
            bl[r * 65 + c4 + 2] = u.z; bl[r * 65 + c4 + 3] = u.w;
        }
        __syncthreads();
        for (int kk = 0; kk < 64; ++kk) {
            float af[4], bf[4];
#pragma unroll
            for (int q = 0; q < 4; ++q) { af[q] = al[(r0 + q) * 65 + kk]; bf[q] = bl[kk * 65 + c0 + q]; }
#pragma unroll
            for (int q = 0; q < 4; ++q)
#pragma unroll
                for (int w2 = 0; w2 < 4; ++w2) accA[q][w2] += af[q] * bf[w2];
        }
    }

    // epilogue: single write of out
#pragma unroll
    for (int q = 0; q < 4; ++q) {
        float4 v;
        float z0 = accG[q][0] + gb[it * 64 + c0 + 0];
        float z1 = accG[q][1] + gb[it * 64 + c0 + 1];
        float z2 = accG[q][2] + gb[it * 64 + c0 + 2];
        float z3 = accG[q][3] + gb[it * 64 + c0 + 3];
        v.x = (accM[q][0] + LRF * accA[q][0]) / (1.f + expf(-z0));
        v.y = (accM[q][1] + LRF * accA[q][1]) / (1.f + expf(-z1));
        v.z = (accM[q][2] + LRF * accA[q][2]) / (1.f + expf(-z2));
        v.w = (accM[q][3] + LRF * accA[q][3]) / (1.f + expf(-z3));
        *(float4*)&out[(growbase + r0 + q) * DD + it * 64 + c0] = v;
    }
}

extern "C" void kernel_launch(void* const* d_in, const int* in_sizes, int n_in,
                              void* d_out, int out_size, void* d_ws, size_t ws_size,
                              hipStream_t stream) {
    const float* x   = (const float*)d_in[0];
    const float* Wc0 = (const float*)d_in[1];
    const float* Wb  = (const float*)d_in[2];
    const float* gw  = (const float*)d_in[3];
    const float* gb  = (const float*)d_in[4];
    float* out  = (float*)d_out;
    float* outW = out + BB * TT * DD;

    float* ws = (float*)d_ws;
    float* A  = ws + OFF_A;
    float* CU = ws + OFF_CU;
    float* G  = ws + OFF_G;
    float* P  = ws + OFF_P;
    float* W  = ws + OFF_W;
    float* WS = ws + OFF_WS;
    float* S  = ws + OFF_S;

    tm_mean<<<(TT * DD) / 256, 256, 0, stream>>>(x, A);
    tm_init<<<(DD * DD) / 256, 256, 0, stream>>>(Wb, Wc0, W, WS);
    tm_gram<<<256, 256, 0, stream>>>(A, G);
    tm_P<<<32, 256, 0, stream>>>(A, W, P, 0);

    for (int p = 0; p < 16; ++p) {
        tm_scanall<<<1, 256, 0, stream>>>(P, G, CU, p);
        if (p < 15) {
            tm_wupd<<<(DD * DD) / 256, 256, 0, stream>>>(A, CU, W, WS, Wb, outW, p, p + 1, 0);
            tm_P<<<32, 256, 0, stream>>>(A, W, P, p + 1);
        }
    }
    tm_wupd<<<(DD * DD) / 256, 256, 0, stream>>>(A, CU, W, WS, Wb, outW, 15, -1, 1);

    tm_score<<<16 * 128, 256, 0, stream>>>(x, A, S);
    tm_fused<<<16 * 256, 256, 0, stream>>>(x, WS, S, CU, gw, gb, out);
}